// Round 7
// baseline (627.331 us; speedup 1.0000x reference)
//
#include <hip/hip_runtime.h>
#include <hip/hip_bf16.h>
#include <cstdint>
#include <cstddef>

#define T_TOK 1024
#define H_DIM 2048
#define NH 32
#define HS 64
#define TH (T_TOK * H_DIM)
#define HH (H_DIM * H_DIM)

using short8 = __attribute__((ext_vector_type(8))) short;
using f32x4  = __attribute__((ext_vector_type(4))) float;
typedef __hip_bfloat16 bf16;

__device__ __forceinline__ float sigmoidf_(float x) { return 1.0f / (1.0f + expf(-x)); }

__device__ __forceinline__ float wsum64(float v) {
#pragma unroll
    for (int m = 32; m; m >>= 1) v += __shfl_xor(v, m, 64);
    return v;
}

// single 16-lane DPP sum (lane bits 0..3) — pure VALU
__device__ __forceinline__ float dpp_add16(float x) {
    int t;
    t = __builtin_amdgcn_update_dpp(0, __float_as_int(x), 0xB1, 0xF, 0xF, true);
    x += __int_as_float(t);
    t = __builtin_amdgcn_update_dpp(0, __float_as_int(x), 0x4E, 0xF, 0xF, true);
    x += __int_as_float(t);
    t = __builtin_amdgcn_update_dpp(0, __float_as_int(x), 0x141, 0xF, 0xF, true);
    x += __int_as_float(t);
    t = __builtin_amdgcn_update_dpp(0, __float_as_int(x), 0x140, 0xF, 0xF, true);
    x += __int_as_float(t);
    return x;
}

// dual interleaved 16-lane DPP sums — two independent chains hide each
// other's VALU latency (round-6 evidence: single chain leaves the SIMD idle)
__device__ __forceinline__ void dpp_add16_pair(float& x, float& y) {
    int tx, ty;
    tx = __builtin_amdgcn_update_dpp(0, __float_as_int(x), 0xB1, 0xF, 0xF, true);
    ty = __builtin_amdgcn_update_dpp(0, __float_as_int(y), 0xB1, 0xF, 0xF, true);
    x += __int_as_float(tx); y += __int_as_float(ty);
    tx = __builtin_amdgcn_update_dpp(0, __float_as_int(x), 0x4E, 0xF, 0xF, true);
    ty = __builtin_amdgcn_update_dpp(0, __float_as_int(y), 0x4E, 0xF, 0xF, true);
    x += __int_as_float(tx); y += __int_as_float(ty);
    tx = __builtin_amdgcn_update_dpp(0, __float_as_int(x), 0x141, 0xF, 0xF, true);
    ty = __builtin_amdgcn_update_dpp(0, __float_as_int(y), 0x141, 0xF, 0xF, true);
    x += __int_as_float(tx); y += __int_as_float(ty);
    tx = __builtin_amdgcn_update_dpp(0, __float_as_int(x), 0x140, 0xF, 0xF, true);
    ty = __builtin_amdgcn_update_dpp(0, __float_as_int(y), 0x140, 0xF, 0xF, true);
    x += __int_as_float(tx); y += __int_as_float(ty);
}

// ---------------- cast big weights fp32 -> bf16 ----------------
struct CastPar { const float* src[4]; bf16* dst[4]; };
__global__ __launch_bounds__(256) void castw_kernel(CastPar p) {
    int z = blockIdx.z;
    const float4* s = (const float4*)p.src[z];
    bf16* d = p.dst[z];
    int i = blockIdx.x * 256 + threadIdx.x;
    float4 v = s[i];
    int b = i * 4;
    d[b + 0] = __float2bfloat16(v.x);
    d[b + 1] = __float2bfloat16(v.y);
    d[b + 2] = __float2bfloat16(v.z);
    d[b + 3] = __float2bfloat16(v.w);
}

// ---------------- coalesced tiled transpose + cast ----------------
struct TPar { const float* src[8]; bf16* dst[8]; int R[8]; int C[8]; };
__global__ __launch_bounds__(256) void transpose_kernel(TPar p) {
    int z = blockIdx.z;
    int R = p.R[z], C = p.C[z];
    int tC = (C + 31) >> 5;
    int tR = (R + 31) >> 5;
    if (blockIdx.x >= tC * tR) return;
    int r0 = (blockIdx.x / tC) * 32, c0 = (blockIdx.x % tC) * 32;
    __shared__ bf16 tl[32][33];
    int tx = threadIdx.x & 31, ty = threadIdx.x >> 5;   // 32 x 8
#pragma unroll
    for (int k = 0; k < 4; k++) {
        int r = r0 + ty + k * 8, c = c0 + tx;
        if (r < R && c < C) tl[ty + k * 8][tx] = __float2bfloat16(p.src[z][(size_t)r * C + c]);
    }
    __syncthreads();
#pragma unroll
    for (int k = 0; k < 4; k++) {
        int r = r0 + tx, c = c0 + ty + k * 8;
        if (r < R && c < C) p.dst[z][(size_t)c * R + r] = tl[tx][ty + k * 8];
    }
}

// ---------------- LayerNorm (ln1) ----------------
__global__ __launch_bounds__(256) void ln_kernel(const float* __restrict__ x,
                                                 const float* __restrict__ w,
                                                 const float* __restrict__ b,
                                                 float* __restrict__ xn,
                                                 float* __restrict__ s1out) {
    int t = blockIdx.x, tid = threadIdx.x;
    const float* xt = x + (size_t)t * H_DIM;
    float v[8]; float s = 0.f, s2 = 0.f;
#pragma unroll
    for (int e = 0; e < 8; e++) { v[e] = xt[tid + 256 * e]; s += v[e]; s2 += v[e] * v[e]; }
    s = wsum64(s); s2 = wsum64(s2);
    __shared__ float ls[8];
    int wid = tid >> 6, ln = tid & 63;
    if (ln == 0) { ls[wid] = s; ls[4 + wid] = s2; }
    __syncthreads();
    s = ls[0] + ls[1] + ls[2] + ls[3];
    s2 = ls[4] + ls[5] + ls[6] + ls[7];
    float mu = s * (1.f / H_DIM);
    float var = s2 * (1.f / H_DIM) - mu * mu;
    float inv = rsqrtf(var + 1e-5f);
#pragma unroll
    for (int e = 0; e < 8; e++) {
        int h = tid + 256 * e;
        float o = (v[e] - mu) * inv * w[h] + b[h];
        xn[(size_t)t * H_DIM + h] = o;
        if (t == T_TOK - 1) s1out[h] = o;
    }
}

// ---------------- token-shift mixes ----------------
struct MixPar { const float* xn; const float* state1; const float* mv[6]; bf16* out[6]; };
__global__ __launch_bounds__(256) void mix_kernel(MixPar p) {
    int t = blockIdx.x, tid = threadIdx.x;
#pragma unroll
    for (int e = 0; e < 8; e++) {
        int h = tid + 256 * e;
        size_t idx = (size_t)t * H_DIM + h;
        float cur = p.xn[idx];
        float prev = (t == 0) ? p.state1[h] : p.xn[idx - H_DIM];
        float sx = prev - cur;
#pragma unroll
        for (int q = 0; q < 6; q++)
            p.out[q][idx] = __float2bfloat16(cur + p.mv[q][h] * sx);
    }
}

// ======== unified pipelined GEMM: C[M,N] = act(X[M,K] @ W[N,K]^T + bias) (+resid) ========
// 4-stage global_load_lds ring, s_waitcnt vmcnt(12), raw barriers. Handles
// K>=32 (stages>=1) via clamped redundant tail issues (keeps vmcnt uniform).
// N<128 allowed: B rows beyond N read defined workspace garbage, guarded at write.
typedef const __attribute__((address_space(1))) uint32_t* gp1_t;
typedef __attribute__((address_space(3))) uint32_t* lp3_t;
__device__ __forceinline__ void async16(const bf16* g, short* l) {
    __builtin_amdgcn_global_load_lds((gp1_t)g, (lp3_t)l, 16, 0, 0);
}

struct UGPar {
    const bf16* X[4]; const bf16* W[4];
    float* outF[4]; bf16* outB[4];
    const float* bias[4]; const float* resid[4];
    int N[4]; int K[4]; int act[4];
};
__global__ __launch_bounds__(256) void ugemm_kernel(UGPar p) {
    int z = blockIdx.z;
    const bf16* __restrict__ X = p.X[z];
    const bf16* __restrict__ W = p.W[z];
    int N = p.N[z], K = p.K[z], act = p.act[z];
    const float* __restrict__ bias = p.bias[z];
    const float* __restrict__ resid = p.resid[z];
    float* __restrict__ outF = p.outF[z];
    bf16* __restrict__ outB = p.outB[z];

    __shared__ short As[4][128 * 32];
    __shared__ short Bs[4][128 * 32];

    int m0 = blockIdx.y * 128, n0 = blockIdx.x * 128;
    int tid = threadIdx.x, lane = tid & 63, wv = tid >> 6;
    int m_off = (wv >> 1) * 64, n_off = (wv & 1) * 64;
    int lr = lane & 15, lq = lane >> 4;

    int srow = lane >> 2;
    int scol = (lane & 3) * 8;
    const bf16* Ag0 = X + (size_t)(m0 + wv * 32 + srow) * K + scol;
    const bf16* Ag1 = Ag0 + (size_t)16 * K;
    const bf16* Bg0 = W + (size_t)(n0 + wv * 32 + srow) * K + scol;
    const bf16* Bg1 = Bg0 + (size_t)16 * K;

    int stages = K >> 5;
    auto issue = [&](int tile, int nb) {
        int kk = tile * 32;
        async16(Ag0 + kk, &As[nb][(wv * 32) * 32]);
        async16(Ag1 + kk, &As[nb][(wv * 32 + 16) * 32]);
        async16(Bg0 + kk, &Bs[nb][(wv * 32) * 32]);
        async16(Bg1 + kk, &Bs[nb][(wv * 32 + 16) * 32]);
    };

    f32x4 acc[4][4];
#pragma unroll
    for (int a = 0; a < 4; a++)
#pragma unroll
        for (int b = 0; b < 4; b++)
#pragma unroll
            for (int r = 0; r < 4; r++) acc[a][b][r] = 0.f;

    issue(0, 0);
    issue(1 < stages ? 1 : stages - 1, 1);
    issue(2 < stages ? 2 : stages - 1, 2);

    for (int it = 0; it < stages; it++) {
        int nt = it + 3;
        int at = nt < stages ? nt : stages - 1;
        issue(at, nt & 3);
        asm volatile("s_waitcnt vmcnt(12)" ::: "memory");
        asm volatile("s_barrier" ::: "memory");
        int buf = it & 3;
        short8 af[4], bfr[4];
#pragma unroll
        for (int mi = 0; mi < 4; mi++)
            af[mi] = *(const short8*)&As[buf][(m_off + mi * 16 + lr) * 32 + lq * 8];
#pragma unroll
        for (int ni = 0; ni < 4; ni++)
            bfr[ni] = *(const short8*)&Bs[buf][(n_off + ni * 16 + lr) * 32 + lq * 8];
#pragma unroll
        for (int mi = 0; mi < 4; mi++)
#pragma unroll
            for (int ni = 0; ni < 4; ni++)
                acc[mi][ni] = __builtin_amdgcn_mfma_f32_16x16x32_bf16(af[mi], bfr[ni], acc[mi][ni], 0, 0, 0);
        asm volatile("s_barrier" ::: "memory");
    }
    asm volatile("s_waitcnt vmcnt(0)" ::: "memory");

#pragma unroll
    for (int mi = 0; mi < 4; mi++)
#pragma unroll
        for (int ni = 0; ni < 4; ni++)
#pragma unroll
            for (int r = 0; r < 4; r++) {
                int rowg = m0 + m_off + mi * 16 + lq * 4 + r;
                int colg = n0 + n_off + ni * 16 + lr;
                if (colg < N) {
                    float v = acc[mi][ni][r];
                    if (bias) v += bias[colg];
                    if (act == 1) v = sigmoidf_(v);
                    else if (act == 2) v = tanhf(v);
                    size_t o = (size_t)rowg * N + colg;
                    if (resid) v += resid[o];
                    if (outF) outF[o] = v;
                    else      outB[o] = __float2bfloat16(v);
                }
            }
}

// ---------------- elementwise prep for the scan ----------------
__global__ __launch_bounds__(64) void prep_kernel(float* __restrict__ k_io, float* __restrict__ v_io,
                                                  const float* __restrict__ v_first,
                                                  const float* __restrict__ vres,
                                                  float* __restrict__ w_io, float* __restrict__ a_io,
                                                  float* __restrict__ as_out,
                                                  const float* __restrict__ k_k,
                                                  const float* __restrict__ k_a,
                                                  const float* __restrict__ w0) {
    int h = blockIdx.x, t = blockIdx.y, i = threadIdx.x;
    int hi = h * HS + i;
    size_t idx = (size_t)t * H_DIM + hi;
    float kf = k_io[idx];
    float kk = kf * k_k[hi];
    float ss = wsum64(kk * kk);
    float kkn = kk / (sqrtf(ss) + 1e-12f);
    float a = a_io[idx];
    k_io[idx] = kf * (1.f + (a - 1.f) * k_a[hi]);
    float vv = v_io[idx];
    v_io[idx] = vv + (v_first[idx] - vv) * vres[idx];
    w_io[idx] = expf(-0.606531f * sigmoidf_(w0[hi] + w_io[idx]));
    a_io[idx] = kkn * a;     // b_seq
    as_out[idx] = -kkn;      // a_seq
}

// ---------------- WKV7 scan: deferred-o dual-DPP pipeline ----------------
// Wave (h,q) q=0..15 owns rows q*4..q*4+3; lane il*16+jb holds S[row][jb*4..+4).
// Per step t: reduce sa_t and o_{t-1} in ONE interleaved dual-DPP chain (the
// two chains hide each other's VALU latency), store y[t-1], S-update is a
// single fma off precomputed pre[e]=fma(v,k,S*w). Critical path excludes the
// o-reduction entirely. 6 asm loads/step, 4 slots; steady wait vmcnt(21)
// (3 slots x (6 loads + 1 store) younger), peel 18/18/19/20.
struct SlotV { f32x4 w, a, b, k, r; float v; };

#define SCAN_ISSUE(sl, tt)                                                              \
    do {                                                                                \
        int tc_ = (tt) < T_TOK ? (tt) : T_TOK - 1;                                      \
        const float* wp_ = w_s + (size_t)tc_ * H_DIM + hb;                              \
        const float* ap_ = as_s + (size_t)tc_ * H_DIM + hb;                             \
        const float* bp_ = b_s + (size_t)tc_ * H_DIM + hb;                              \
        const float* kp_ = k_s + (size_t)tc_ * H_DIM + hb;                              \
        const float* rp_ = r_s + (size_t)tc_ * H_DIM + hb;                              \
        const float* vp_ = v_s + (size_t)tc_ * H_DIM + hb;                              \
        asm volatile("global_load_dwordx4 %0, %1, %2" : "=v"((sl).w) : "v"(jow), "s"(wp_)); \
        asm volatile("global_load_dwordx4 %0, %1, %2" : "=v"((sl).a) : "v"(jow), "s"(ap_)); \
        asm volatile("global_load_dwordx4 %0, %1, %2" : "=v"((sl).b) : "v"(jow), "s"(bp_)); \
        asm volatile("global_load_dwordx4 %0, %1, %2" : "=v"((sl).k) : "v"(jow), "s"(kp_)); \
        asm volatile("global_load_dwordx4 %0, %1, %2" : "=v"((sl).r) : "v"(jow), "s"(rp_)); \
        asm volatile("global_load_dword %0, %1, %2" : "=v"((sl).v) : "v"(rowoff), "s"(vp_)); \
    } while (0)

#define SCAN_PIN(sl)                                                                    \
    asm volatile("" : "+v"((sl).w), "+v"((sl).a), "+v"((sl).b), "+v"((sl).k),           \
                      "+v"((sl).r), "+v"((sl).v))

// full step with deferred-o carry `ov` (holds o_{t-1} pre-reduction)
#define SCAN_STEP(d, t, W)                                                              \
    do {                                                                                \
        asm volatile("s_waitcnt vmcnt(" W ")");                                         \
        SCAN_PIN(sv[d]);                                                                \
        float Sw0 = S[0] * sv[d].w[0], Sw1 = S[1] * sv[d].w[1];                         \
        float Sw2 = S[2] * sv[d].w[2], Sw3 = S[3] * sv[d].w[3];                         \
        float pA = Sw0 * sv[d].a[0], pB = Sw2 * sv[d].a[2];                             \
        pA = fmaf(Sw1, sv[d].a[1], pA); pB = fmaf(Sw3, sv[d].a[3], pB);                 \
        float sa = pA + pB;                                                             \
        float pre0 = fmaf(sv[d].v, sv[d].k[0], Sw0);                                    \
        float pre1 = fmaf(sv[d].v, sv[d].k[1], Sw1);                                    \
        float pre2 = fmaf(sv[d].v, sv[d].k[2], Sw2);                                    \
        float pre3 = fmaf(sv[d].v, sv[d].k[3], Sw3);                                    \
        dpp_add16_pair(sa, ov);                                                         \
        {                                                                               \
            const float* yp_ = y + (size_t)((t) - 1) * H_DIM + hb;                      \
            asm volatile("global_store_dword %0, %1, %2" :: "v"(rowoff), "v"(ov), "s"(yp_) : "memory"); \
        }                                                                               \
        S[0] = fmaf(sa, sv[d].b[0], pre0);                                              \
        S[1] = fmaf(sa, sv[d].b[1], pre1);                                              \
        S[2] = fmaf(sa, sv[d].b[2], pre2);                                              \
        S[3] = fmaf(sa, sv[d].b[3], pre3);                                              \
        float qA = S[0] * sv[d].r[0], qB = S[2] * sv[d].r[2];                           \
        qA = fmaf(S[1], sv[d].r[1], qA); qB = fmaf(S[3], sv[d].r[3], qB);               \
        ov = qA + qB;                                                                   \
        SCAN_ISSUE(sv[d], (t) + 4);                                                     \
    } while (0)

__global__ __launch_bounds__(64) void scan_kernel(const float* __restrict__ w_s,
                                                  const float* __restrict__ k_s,
                                                  const float* __restrict__ v_s,
                                                  const float* __restrict__ as_s,
                                                  const float* __restrict__ b_s,
                                                  const float* __restrict__ r_s,
                                                  const float* __restrict__ s2in,
                                                  float* __restrict__ y,
                                                  float* __restrict__ s2out) {
    int h = blockIdx.x, q = blockIdx.y;
    int lane = threadIdx.x;
    int il = lane >> 4, jb = lane & 15;
    int row = q * 4 + il;
    int jo = jb * 4;
    int hb = h * HS;
    int jow = jo * 4;
    int rowoff = row * 4;

    float S[4];
    {
        const float* s0 = s2in + (size_t)h * HS * HS + (size_t)row * HS + jo;
        float4 t0 = *(const float4*)s0;
        S[0] = t0.x; S[1] = t0.y; S[2] = t0.z; S[3] = t0.w;
    }

    SlotV sv[4];
    SCAN_ISSUE(sv[0], 0);
    SCAN_ISSUE(sv[1], 1);
    SCAN_ISSUE(sv[2], 2);
    SCAN_ISSUE(sv[3], 3);

    float ov;
    // peeled step 0: no carried o, no store
    {
        asm volatile("s_waitcnt vmcnt(18)");
        SCAN_PIN(sv[0]);
        float Sw0 = S[0] * sv[0].w[0], Sw1 = S[1] * sv[0].w[1];
        float Sw2 = S[2] * sv[0].w[2], Sw3 = S[3] * sv[0].w[3];
        float pA = Sw0 * sv[0].a[0], pB = Sw2 * sv[0].a[2];
        pA = fmaf(Sw1, sv[0].a[1], pA); pB = fmaf(Sw3, sv[0].a[3], pB);
        float sa = dpp_add16(pA + pB);
        float pre0 = fmaf(sv[0].v, sv[0].k[0], Sw0);
        float pre1 = fmaf(sv[0].v, sv[0].k[1], Sw1);
        float pre2 = fmaf(sv[0].v, sv[0].k[2], Sw2);
        float pre3 = fmaf(sv[0].v, sv[0].k[3], Sw3);
        S[0] = fmaf(sa, sv[0].b[0], pre0);
        S[1] = fmaf(sa, sv[0].b[1], pre1);
        S[2] = fmaf(sa, sv[0].b[2], pre2);
        S[3] = fmaf(sa, sv[0].b[3], pre3);
        float qA = S[0] * sv[0].r[0], qB = S[2] * sv[0].r[2];
        qA = fmaf(S[1], sv[0].r[1], qA); qB = fmaf(S[3], sv[0].r[3], qB);
        ov = qA + qB;
        SCAN_ISSUE(sv[0], 4);
    }
    SCAN_STEP(1, 1, "18");
    SCAN_STEP(2, 2, "19");
    SCAN_STEP(3, 3, "20");
    for (int tb = 4; tb < T_TOK; tb += 4) {
        SCAN_STEP(0, tb + 0, "21");
        SCAN_STEP(1, tb + 1, "21");
        SCAN_STEP(2, tb + 2, "21");
        SCAN_STEP(3, tb + 3, "21");
    }
    // final deferred o (step 1023)
    {
        float o = dpp_add16(ov);
        const float* yp_ = y + (size_t)(T_TOK - 1) * H_DIM + hb;
        asm volatile("global_store_dword %0, %1, %2" :: "v"(rowoff), "v"(o), "s"(yp_) : "memory");
    }
    asm volatile("s_waitcnt vmcnt(0)" ::: "memory");

    {
        float* so = s2out + (size_t)h * HS * HS + (size_t)row * HS + jo;
        float4 t0;
        t0.x = S[0]; t0.y = S[1]; t0.z = S[2]; t0.w = S[3];
        *(float4*)so = t0;
    }
}

// ---------------- groupnorm + bonus + gate -> bf16 ----------------
__global__ __launch_bounds__(64) void post_kernel(const float* __restrict__ y,
                                                  const float* __restrict__ r_s,
                                                  const float* __restrict__ k_s,
                                                  const float* __restrict__ v_s,
                                                  const float* __restrict__ g_s,
                                                  const float* __restrict__ r_k,
                                                  const float* __restrict__ lnw,
                                                  const float* __restrict__ lnb,
                                                  bf16* __restrict__ ybig) {
    int h = blockIdx.x, t = blockIdx.y, i = threadIdx.x;
    int hi = h * HS + i;
    size_t idx = (size_t)t * H_DIM + hi;
    float yv = y[idx];
    float mu = wsum64(yv) * (1.f / HS);
    float d = yv - mu;
    float var = wsum64(d * d) * (1.f / HS);
    float yn = d * rsqrtf(var + 0.00064f);
    float bd = wsum64(r_s[idx] * k_s[idx] * r_k[hi]);
    float val = (yn * lnw[hi] + lnb[hi] + bd * v_s[idx]) * g_s[idx];
    ybig[idx] = __float2bfloat16(val);
}

// ---------------- launcher ----------------
extern "C" void kernel_launch(void* const* d_in, const int* in_sizes, int n_in,
                              void* d_out, int out_size, void* d_ws, size_t ws_size,
                              hipStream_t stream) {
    const float* x      = (const float*)d_in[0];
    const float* state1 = (const float*)d_in[1];
    const float* state2 = (const float*)d_in[2];
    const float* vfirst = (const float*)d_in[3];
    const float* x_r = (const float*)d_in[4];
    const float* x_w = (const float*)d_in[5];
    const float* x_k = (const float*)d_in[6];
    const float* x_v = (const float*)d_in[7];
    const float* x_a = (const float*)d_in[8];
    const float* x_g = (const float*)d_in[9];
    const float* W_r = (const float*)d_in[10];
    const float* W_k = (const float*)d_in[11];
    const float* W_v = (const float*)d_in[12];
    const float* W_o = (const float*)d_in[13];
    const float* w0 = (const float*)d_in[14];
    const float* w1 = (const float*)d_in[15];
    const float* w2 = (const float*)d_in[16];
    const float* a0 = (const float*)d_in[17];
    const float* a1 = (const float*)d_in[18];
    const float* a2 = (const float*)d_in[19];
    const float* v0 = (const float*)d_in[20];
    const float* v1 = (const float*)d_in[21];
    const float* v2 = (const float*)d_in[22];
    const float* g1 = (const float*)d_in[23];
    const float* g2 = (const float*)d_in[24];
    const float* k_k = (const float*)d_in[25];
    const float* k_a = (const float*)d_in[26];
    const float* r_k = (const float*)d_in[27];
    const float* ln_x_w = (const float*)d_in[28];
    const float* ln_x_b = (const float*)d_in[29];
    const float* ln1_w = (const float*)d_in[30];
    const float* ln1_b = (const float*)d_in[31];

    float* out0 = (float*)d_out;
    float* out1 = out0 + TH;
    float* out2 = out1 + H_DIM;
    float* out3 = out2 + NH * HS * HS;

    float* F = (float*)d_ws;
    float* xn   = F;                          // dead after mix; reused as as_s
    float* as_s = F;
    float* rb   = F + (size_t)1 * TH;
    float* kb   = F + (size_t)2 * TH;
    float* vb   = F + (size_t)3 * TH;
    float* ab   = F + (size_t)4 * TH;
    float* wpre = F + (size_t)5 * TH;
    float* vresb= F + (size_t)6 * TH;
    float* gb   = F + (size_t)7 * TH;
    float* yb   = F + (size_t)8 * TH;
    bf16* B = (bf16*)(F + (size_t)9 * TH);
    bf16 *xrb = B, *xwb = B + (size_t)TH, *xkb = B + (size_t)2 * TH,
         *xvb = B + (size_t)3 * TH, *xab = B + (size_t)4 * TH, *xgb = B + (size_t)5 * TH;
    bf16* Wrb = B + (size_t)6 * TH;
    bf16* Wkb = Wrb + (size_t)HH;
    bf16* Wvb = Wkb + (size_t)HH;
    bf16* Wob = Wvb + (size_t)HH;
    bf16* pp = Wob + (size_t)HH;
    bf16* a1T = pp; pp += (size_t)H_DIM * 64;
    bf16* w1T = pp; pp += (size_t)H_DIM * 64;
    bf16* v1T = pp; pp += (size_t)H_DIM * 32;
    bf16* g1T = pp; pp += (size_t)H_DIM * 128;
    bf16* a2T = pp; pp += (size_t)H_DIM * 64;
    bf16* w2T = pp; pp += (size_t)H_DIM * 64;
    bf16* v2T = pp; pp += (size_t)H_DIM * 32;
    bf16* g2T = pp; pp += (size_t)H_DIM * 128;
    bf16* amid = pp; pp += (size_t)T_TOK * 64;
    bf16* wmid = pp; pp += (size_t)T_TOK * 64;
    bf16* vmid = pp; pp += (size_t)T_TOK * 32;
    bf16* gmid = pp; pp += (size_t)T_TOK * 128;
    bf16* ybig = pp; pp += (size_t)TH;
    bf16* slack = pp; pp += (size_t)128 * H_DIM;   // OOB-read slack for small-N B tiles
    (void)slack;

    // 1. cast big weights to bf16
    CastPar cp;
    cp.src[0] = W_r; cp.src[1] = W_k; cp.src[2] = W_v; cp.src[3] = W_o;
    cp.dst[0] = Wrb; cp.dst[1] = Wkb; cp.dst[2] = Wvb; cp.dst[3] = Wob;
    castw_kernel<<<dim3(HH / 4 / 256, 1, 4), 256, 0, stream>>>(cp);

    // 2. coalesced transpose + cast small weights
    TPar tp;
    tp.src[0] = a1; tp.dst[0] = a1T; tp.R[0] = H_DIM; tp.C[0] = 64;
    tp.src[1] = w1; tp.dst[1] = w1T; tp.R[1] = H_DIM; tp.C[1] = 64;
    tp.src[2] = v1; tp.dst[2] = v1T; tp.R[2] = H_DIM; tp.C[2] = 32;
    tp.src[3] = g1; tp.dst[3] = g1T; tp.R[3] = H_DIM; tp.C[3] = 128;
    tp.src[4] = a2; tp.dst[4] = a2T; tp.R[4] = 64;  tp.C[4] = H_DIM;
    tp.src[5] = w2; tp.dst[5] = w2T; tp.R[5] = 64;  tp.C[5] = H_DIM;
    tp.src[6] = v2; tp.dst[6] = v2T; tp.R[6] = 32;  tp.C[6] = H_DIM;
    tp.src[7] = g2; tp.dst[7] = g2T; tp.R[7] = 128; tp.C[7] = H_DIM;
    transpose_kernel<<<dim3(256, 1, 8), 256, 0, stream>>>(tp);

    // 3. LayerNorm
    ln_kernel<<<dim3(T_TOK), 256, 0, stream>>>(x, ln1_w, ln1_b, xn, out1);

    // 4. token-shift mixes
    MixPar mp; mp.xn = xn; mp.state1 = state1;
    mp.mv[0] = x_r; mp.mv[1] = x_w; mp.mv[2] = x_k; mp.mv[3] = x_v; mp.mv[4] = x_a; mp.mv[5] = x_g;
    mp.out[0] = xrb; mp.out[1] = xwb; mp.out[2] = xkb; mp.out[3] = xvb; mp.out[4] = xab; mp.out[5] = xgb;
    mix_kernel<<<dim3(T_TOK), 256, 0, stream>>>(mp);

    // 5. r,k,v GEMMs
    UGPar gp{};
    gp.X[0] = xrb; gp.W[0] = Wrb; gp.outF[0] = rb; gp.N[0] = H_DIM; gp.K[0] = H_DIM;
    gp.X[1] = xkb; gp.W[1] = Wkb; gp.outF[1] = kb; gp.N[1] = H_DIM; gp.K[1] = H_DIM;
    gp.X[2] = xvb; gp.W[2] = Wvb; gp.outF[2] = vb; gp.N[2] = H_DIM; gp.K[2] = H_DIM;
    ugemm_kernel<<<dim3(16, 8, 3), 256, 0, stream>>>(gp);

    // 6. low-rank stage 1 (pipelined now)
    UGPar s1{};
    s1.X[0] = xab; s1.W[0] = a1T; s1.outB[0] = amid; s1.N[0] = 64;  s1.K[0] = H_DIM; s1.act[0] = 0;
    s1.X[1] = xwb; s1.W[1] = w1T; s1.outB[1] = wmid; s1.N[1] = 64;  s1.K[1] = H_DIM; s1.act[1] = 2;
    s1.X[2] = xvb; s1.W[2] = v1T; s1.outB[2] = vmid; s1.N[2] = 32;  s1.K[2] = H_DIM; s1.act[2] = 0;
    s1.X[3] = xgb; s1.W[3] = g1T; s1.outB[3] = gmid; s1.N[3] = 128; s1.K[3] = H_DIM; s1.act[3] = 1;
    ugemm_kernel<<<dim3(1, 8, 4), 256, 0, stream>>>(s1);

    // 7. low-rank stage 2
    UGPar s2{};
    s2.X[0] = amid; s2.W[0] = a2T; s2.outF[0] = ab;    s2.N[0] = H_DIM; s2.K[0] = 64;  s2.act[0] = 1; s2.bias[0] = a0;
    s2.X[1] = wmid; s2.W[1] = w2T; s2.outF[1] = wpre;  s2.N[1] = H_DIM; s2.K[1] = 64;  s2.act[1] = 0;
    s2.X[2] = vmid; s2.W[2] = v2T; s2.outF[2] = vresb; s2.N[2] = H_DIM; s2.K[2] = 32;  s2.act[2] = 1; s2.bias[2] = v0;
    s2.X[3] = gmid; s2.W[3] = g2T; s2.outF[3] = gb;    s2.N[3] = H_DIM; s2.K[3] = 128; s2.act[3] = 0;
    ugemm_kernel<<<dim3(16, 8, 4), 256, 0, stream>>>(s2);

    // 8. elementwise prep
    prep_kernel<<<dim3(NH, T_TOK), 64, 0, stream>>>(kb, vb, vfirst, vresb, wpre, ab, as_s, k_k, k_a, w0);

    // 9. scan (deferred-o dual-DPP)
    scan_kernel<<<dim3(NH, 16), 64, 0, stream>>>(wpre, kb, vb, as_s, ab, rb, state2, yb, out2);

    // 10. groupnorm + bonus + gate
    post_kernel<<<dim3(NH, T_TOK), 64, 0, stream>>>(yb, rb, kb, vb, gb, r_k, ln_x_w, ln_x_b, ybig);

    // 11. final GEMM with residual
    UGPar go{};
    go.X[0] = ybig; go.W[0] = Wob; go.outF[0] = out0; go.N[0] = H_DIM; go.K[0] = H_DIM; go.resid[0] = x;
    ugemm_kernel<<<dim3(16, 8, 1), 256, 0, stream>>>(go);

    // 12. v_first passthrough
    hipMemcpyAsync(out3, (const void*)vfirst, (size_t)TH * sizeof(float),
                   hipMemcpyDeviceToDevice, stream);
}